// Round 22
// baseline (163.579 us; speedup 1.0000x reference)
//
#include <hip/hip_runtime.h>

#define HH 1024
#define WW 1024
#define NIMG 12
#define ZSPLIT 6           // wave handles images z and z+6
#define OUTC 50            // output cols per wave (lanes 7..56)
#define NSTRIP 21          // ceil(1024/50)

// fwd8: F(l) = sum of values at lanes l..l+7 (valid for lane <= 56), balanced
// pairwise tree — identical grouping to all previous rounds (bitwise-stable).
__device__ __forceinline__ float fwd8(float a) {
  a += __shfl_down(a, 1, 64);
  a += __shfl_down(a, 2, 64);
  a += __shfl_down(a, 4, 64);
  return a;
}

// Zero-padded pixel load.
__device__ __forceinline__ float load_px(const float* __restrict__ s, int ry, int cl) {
  if ((unsigned)ry < (unsigned)HH && (unsigned)cl < (unsigned)WW)
    return s[(size_t)ry * WW + cl];
  return 0.0f;
}

// first-wins argmin combine: keep a unless |b| strictly smaller (tie -> a).
__device__ __forceinline__ float winner(float a, float b) {
  return (fabsf(b) < fabsf(a)) ? b : a;
}

__device__ __forceinline__ float out_px(float ua, float ub, float uc,
                                        float da, float db, float dc,
                                        float lh0, float rh0, float w0) {
  const float ih = 1.0f / 120.0f, iq = 1.0f / 64.0f;
  const float nw0 = -w0;
  const float Ls = ua + da - lh0;
  const float Rs = ub + db - rh0;
  const float Us = ua + ub - uc;
  const float Ds = da + db - dc;
  float d0 = fmaf(Ls, ih, nw0);
  float d1 = fmaf(Rs, ih, nw0);
  float d2 = fmaf(Us, ih, nw0);
  float d3 = fmaf(Ds, ih, nw0);
  float d4 = fmaf(ua, iq, nw0);
  float d5 = fmaf(ub, iq, nw0);
  float d6 = fmaf(da, iq, nw0);
  float d7 = fmaf(db, iq, nw0);
  float w01 = winner(d0, d1), w23 = winner(d2, d3);
  float w45 = winner(d4, d5), w67 = winner(d6, d7);
  float bd = winner(winner(w01, w23), winner(w45, w67));
  return w0 + bd;
}

// One SWF step, TWO-STREAM version: each wave runs R15's exact pipeline on the
// same (strip, 32-row chunk) of TWO images (z, z+6). Index math shared; data
// chains independent -> cross-stream ILP covers each stream's DS-chain stalls
// without needing more resident waves (residency measured stuck at ~2.7/SIMD
// across R15/R17/R19/R21). Per-stream arithmetic verbatim R15 -> bitwise-
// identical output.
__global__ __launch_bounds__(256, 3) void swf_step(const float* __restrict__ src,
                                                   float* __restrict__ dst) {
  const int lane = threadIdx.x & 63;
  const int wid  = threadIdx.x >> 6;
  const int cl   = blockIdx.x * OUTC - 7 + lane;       // load col
  const int y0   = (blockIdx.y * 4 + wid) * 32;        // 32 chunks x 32 rows
  const float* sA = src + (size_t)blockIdx.z * HH * WW;
  const float* sB = sA + (size_t)ZSPLIT * HH * WW;
  float* dA       = dst + (size_t)blockIdx.z * HH * WW;
  float* dB       = dA + (size_t)ZSPLIT * HH * WW;

  const bool writeOK = (lane >= 7) && (lane <= 56) && (cl < WW);

  float rlhA[16], rrhA[16], rwA[16];
  float rlhB[16], rrhB[16], rwB[16];

  // Prologue: rows y0-8 .. y0+6 into slot row&15 = (j+8)&15 (y0 % 32 == 0).
  #pragma unroll
  for (int j = 0; j < 15; ++j) {
    const int slot = (j + 8) & 15;
    const int ry = y0 - 8 + j;
    float wcA = load_px(sA, ry, cl);
    float wcB = load_px(sB, ry, cl);
    float fA = fwd8(wcA);
    float fB = fwd8(wcB);
    rlhA[slot] = __shfl_up(fA, 7, 64);
    rlhB[slot] = __shfl_up(fB, 7, 64);
    rrhA[slot] = fA;  rwA[slot] = wcA;
    rrhB[slot] = fB;  rwB[slot] = wcB;
  }

  // Sliding accumulators for "previous output row" y0-1 (per stream).
  float uaA = 0.f, ubA = 0.f, ucA = 0.f, daA = 0.f, dbA = 0.f, dcA = 0.f;
  float uaB = 0.f, ubB = 0.f, ucB = 0.f, daB = 0.f, dbB = 0.f, dcB = 0.f;
  #pragma unroll
  for (int j = 0; j < 8; ++j) {
    const int sl = (8 + j) & 15;
    uaA += rlhA[sl]; ubA += rrhA[sl]; ucA += rwA[sl];
    uaB += rlhB[sl]; ubB += rrhB[sl]; ucB += rwB[sl];
  }
  #pragma unroll
  for (int j = 0; j < 8; ++j) {
    const int sl = (15 + j) & 15;
    daA += rlhA[sl]; dbA += rrhA[sl]; dcA += rwA[sl];
    daB += rlhB[sl]; dbB += rrhB[sl]; dcB += rwB[sl];
  }

  // Load pipes: slot(row) = (row - y0 - 7) & 7. Prime rows y0+7 .. y0+12.
  float pipeA[8], pipeB[8];
  #pragma unroll
  for (int k = 0; k < 6; ++k) {
    pipeA[k] = load_px(sA, y0 + 7 + k, cl);
    pipeB[k] = load_px(sB, y0 + 7 + k, cl);
  }

  #pragma unroll 1
  for (int yb = 0; yb < 32; yb += 16) {
    #pragma unroll
    for (int i = 0; i < 16; i += 2) {   // rows y, y+1, both streams
      const int y = y0 + yb + i;
      // prefetch rows y+13, y+14 into both pipes (consumed 3 pair-iters later)
      pipeA[(i + 6) & 7] = load_px(sA, y + 13, cl);
      pipeB[(i + 6) & 7] = load_px(sB, y + 13, cl);
      pipeA[(i + 7) & 7] = load_px(sA, y + 14, cl);
      pipeB[(i + 7) & 7] = load_px(sB, y + 14, cl);

      const int ls0 = (i + 7) & 15;
      const int ls1 = (i + 8) & 15;

      // rows y+7, y+8: four independent fwd8 chains (2 rows x 2 streams)
      const float t0A = pipeA[i & 7];
      const float t1A = pipeA[(i + 1) & 7];
      const float t0B = pipeB[i & 7];
      const float t1B = pipeB[(i + 1) & 7];
      float f0A = fwd8(t0A);
      float f0B = fwd8(t0B);
      float f1A = fwd8(t1A);
      float f1B = fwd8(t1B);
      float l0A = __shfl_up(f0A, 7, 64);
      float l0B = __shfl_up(f0B, 7, 64);
      float l1A = __shfl_up(f1A, 7, 64);
      float l1B = __shfl_up(f1B, 7, 64);

      // commit row y+7 (slot ls0 held dead row y-9)
      rlhA[ls0] = l0A; rrhA[ls0] = f0A; rwA[ls0] = t0A;
      rlhB[ls0] = l0B; rrhB[ls0] = f0B; rwB[ls0] = t0B;
      // row y+8 stays in temps: slot ls1 still live (row y-8, read below)

      // ---- row y, stream A: slide y-1 -> y (reads OLD slot ls1 = row y-8)
      uaA += rlhA[i];   uaA -= rlhA[ls1];
      ubA += rrhA[i];   ubA -= rrhA[ls1];
      ucA += rwA [i];   ucA -= rwA [ls1];
      daA += rlhA[ls0]; daA -= rlhA[(i + 15) & 15];
      dbA += rrhA[ls0]; dbA -= rrhA[(i + 15) & 15];
      dcA += rwA [ls0]; dcA -= rwA [(i + 15) & 15];
      const float o0A = out_px(uaA, ubA, ucA, daA, dbA, dcA, rlhA[i], rrhA[i], rwA[i]);

      // ---- row y, stream B
      uaB += rlhB[i];   uaB -= rlhB[ls1];
      ubB += rrhB[i];   ubB -= rrhB[ls1];
      ucB += rwB [i];   ucB -= rwB [ls1];
      daB += rlhB[ls0]; daB -= rlhB[(i + 15) & 15];
      dbB += rrhB[ls0]; dbB -= rrhB[(i + 15) & 15];
      dcB += rwB [ls0]; dcB -= rwB [(i + 15) & 15];
      const float o0B = out_px(uaB, ubB, ucB, daB, dbB, dcB, rlhB[i], rrhB[i], rwB[i]);

      // commit row y+8 (row y-8 now dead)
      rlhA[ls1] = l1A; rrhA[ls1] = f1A; rwA[ls1] = t1A;
      rlhB[ls1] = l1B; rrhB[ls1] = f1B; rwB[ls1] = t1B;

      // ---- row y+1, stream A
      const int i1 = i + 1;
      uaA += rlhA[i1];  uaA -= rlhA[(i1 + 8) & 15];
      ubA += rrhA[i1];  ubA -= rrhA[(i1 + 8) & 15];
      ucA += rwA [i1];  ucA -= rwA [(i1 + 8) & 15];
      daA += rlhA[ls1]; daA -= rlhA[i];
      dbA += rrhA[ls1]; dbA -= rrhA[i];
      dcA += rwA [ls1]; dcA -= rwA [i];
      const float o1A = out_px(uaA, ubA, ucA, daA, dbA, dcA, rlhA[i1], rrhA[i1], rwA[i1]);

      // ---- row y+1, stream B
      uaB += rlhB[i1];  uaB -= rlhB[(i1 + 8) & 15];
      ubB += rrhB[i1];  ubB -= rrhB[(i1 + 8) & 15];
      ucB += rwB [i1];  ucB -= rwB [(i1 + 8) & 15];
      daB += rlhB[ls1]; daB -= rlhB[i];
      dbB += rrhB[ls1]; dbB -= rrhB[i];
      dcB += rwB [ls1]; dcB -= rwB [i];
      const float o1B = out_px(uaB, ubB, ucB, daB, dbB, dcB, rlhB[i1], rrhB[i1], rwB[i1]);

      if (writeOK) {
        dA[(size_t)y * WW + cl]       = o0A;
        dA[(size_t)(y + 1) * WW + cl] = o1A;
        dB[(size_t)y * WW + cl]       = o0B;
        dB[(size_t)(y + 1) * WW + cl] = o1B;
      }
    }
  }
}

extern "C" void kernel_launch(void* const* d_in, const int* in_sizes, int n_in,
                              void* d_out, int out_size, void* d_ws, size_t ws_size,
                              hipStream_t stream) {
  const float* in = (const float*)d_in[0];
  float* out = (float*)d_out;
  float* ws  = (float*)d_ws;   // 12*1024*1024*4 = 50.3 MB scratch

  dim3 grid(NSTRIP, 8, ZSPLIT);  // 21 strips, 8 ygroups x4 waves x32 rows, 6 z (x2 images)
  dim3 block(256);

  swf_step<<<grid, block, 0, stream>>>(in, out);
  swf_step<<<grid, block, 0, stream>>>(out, ws);
  swf_step<<<grid, block, 0, stream>>>(ws, out);
}

// Round 23
// 123.237 us; speedup vs baseline: 1.3274x; 1.3274x over previous
//
#include <hip/hip_runtime.h>

#define HH 1024
#define WW 1024
#define NIMG 12
#define OUTC 50            // output cols per wave (lanes 7..56)
#define NSTRIP 21          // ceil(1024/50)

// fwd8: F(l) = sum of values at lanes l..l+7 (valid for lane <= 56), balanced
// pairwise tree — identical grouping to all previous rounds (bitwise-stable).
__device__ __forceinline__ float fwd8(float a) {
  a += __shfl_down(a, 1, 64);
  a += __shfl_down(a, 2, 64);
  a += __shfl_down(a, 4, 64);
  return a;
}

// Zero-padded pixel load.
__device__ __forceinline__ float load_px(const float* __restrict__ s, int ry, int cl) {
  if ((unsigned)ry < (unsigned)HH && (unsigned)cl < (unsigned)WW)
    return s[(size_t)ry * WW + cl];
  return 0.0f;
}

// first-wins argmin combine: keep a unless |b| strictly smaller (tie -> a).
__device__ __forceinline__ float winner(float a, float b) {
  return (fabsf(b) < fabsf(a)) ? b : a;
}

__device__ __forceinline__ float out_px(float ua, float ub, float uc,
                                        float da, float db, float dc,
                                        float lh0, float rh0, float w0) {
  const float ih = 1.0f / 120.0f, iq = 1.0f / 64.0f;
  const float nw0 = -w0;
  const float Ls = ua + da - lh0;
  const float Rs = ub + db - rh0;
  const float Us = ua + ub - uc;
  const float Ds = da + db - dc;
  float d0 = fmaf(Ls, ih, nw0);
  float d1 = fmaf(Rs, ih, nw0);
  float d2 = fmaf(Us, ih, nw0);
  float d3 = fmaf(Ds, ih, nw0);
  float d4 = fmaf(ua, iq, nw0);
  float d5 = fmaf(ub, iq, nw0);
  float d6 = fmaf(da, iq, nw0);
  float d7 = fmaf(db, iq, nw0);
  float w01 = winner(d0, d1), w23 = winner(d2, d3);
  float w45 = winner(d4, d5), w67 = winner(d6, d7);
  float bd = winner(winner(w01, w23), winner(w45, w67));
  return w0 + bd;
}

// One SWF step, halo-lane tiling (R15 arithmetic verbatim) with 2-WAVE
// workgroups: 128-thread blocks pack into CU wave slots at finer granularity
// than 256-thread blocks. R15's 2016x4-wave grid = 7.9 blocks/CU nominal but
// measured residency ~2.7 waves/SIMD — hypothesis: 4-wave workgroup granule
// (4 contiguous slots + 4xVGPR at once) fragments capacity under departure
// skew. Same total waves (8064), same per-wave work (32 rows).
__global__ __launch_bounds__(128) void swf_step(const float* __restrict__ src,
                                                float* __restrict__ dst) {
  const int lane = threadIdx.x & 63;
  const int wid  = threadIdx.x >> 6;                   // 0..1
  const int cl   = blockIdx.x * OUTC - 7 + lane;       // load col
  const int y0   = (blockIdx.y * 2 + wid) * 32;        // 32 chunks x 32 rows
  const float* s = src + (size_t)blockIdx.z * HH * WW;
  float* d       = dst + (size_t)blockIdx.z * HH * WW;

  const bool writeOK = (lane >= 7) && (lane <= 56) && (cl < WW);

  float rlh[16], rrh[16], rw[16];

  // Prologue: rows y0-8 .. y0+6 into slot row&15 = (j+8)&15 (y0 % 32 == 0).
  #pragma unroll
  for (int j = 0; j < 15; ++j) {
    const int slot = (j + 8) & 15;
    float wc = load_px(s, y0 - 8 + j, cl);
    float f  = fwd8(wc);
    rlh[slot] = __shfl_up(f, 7, 64);
    rrh[slot] = f;
    rw [slot] = wc;
  }

  // Sliding accumulators for "previous output row" y0-1:
  //   u* over rows y0-8..y0-1 (slots 8..15), d* over rows y0-1..y0+6 (15,0..6)
  float ua = 0.f, ub = 0.f, uc = 0.f, da = 0.f, db = 0.f, dc = 0.f;
  #pragma unroll
  for (int j = 0; j < 8; ++j) {
    const int sl = (8 + j) & 15;
    ua += rlh[sl]; ub += rrh[sl]; uc += rw[sl];
  }
  #pragma unroll
  for (int j = 0; j < 8; ++j) {
    const int sl = (15 + j) & 15;
    da += rlh[sl]; db += rrh[sl]; dc += rw[sl];
  }

  // Load pipe: slot(row) = (row - y0 - 7) & 7. Prime rows y0+7 .. y0+12.
  float pipe[8];
  #pragma unroll
  for (int k = 0; k < 6; ++k) pipe[k] = load_px(s, y0 + 7 + k, cl);

  #pragma unroll 1
  for (int yb = 0; yb < 32; yb += 16) {
    #pragma unroll
    for (int i = 0; i < 16; i += 2) {   // rows y, y+1
      const int y = y0 + yb + i;
      // prefetch rows y+13, y+14 (consumed 3 pair-iters later)
      pipe[(i + 6) & 7] = load_px(s, y + 13, cl);
      pipe[(i + 7) & 7] = load_px(s, y + 14, cl);

      const int ls0 = (i + 7) & 15;
      const int ls1 = (i + 8) & 15;

      // rows y+7, y+8: two independent fwd8 chains
      const float t0 = pipe[i & 7];
      const float t1 = pipe[(i + 1) & 7];
      float f0 = fwd8(t0);
      float f1 = fwd8(t1);
      float l0 = __shfl_up(f0, 7, 64);
      float l1 = __shfl_up(f1, 7, 64);

      // commit row y+7 (slot ls0 held dead row y-9)
      rlh[ls0] = l0; rrh[ls0] = f0; rw[ls0] = t0;
      // row y+8 stays in temps: slot ls1 still live (row y-8, read below)

      // ---- row y: slide windows y-1 -> y (reads OLD slot ls1 = row y-8)
      ua += rlh[i];   ua -= rlh[ls1];
      ub += rrh[i];   ub -= rrh[ls1];
      uc += rw [i];   uc -= rw [ls1];
      da += rlh[ls0]; da -= rlh[(i + 15) & 15];
      db += rrh[ls0]; db -= rrh[(i + 15) & 15];
      dc += rw [ls0]; dc -= rw [(i + 15) & 15];
      const float o0 = out_px(ua, ub, uc, da, db, dc, rlh[i], rrh[i], rw[i]);

      // commit row y+8 (row y-8 now dead)
      rlh[ls1] = l1; rrh[ls1] = f1; rw[ls1] = t1;

      // ---- row y+1: slide windows y -> y+1
      const int i1 = i + 1;
      ua += rlh[i1];  ua -= rlh[(i1 + 8) & 15];
      ub += rrh[i1];  ub -= rrh[(i1 + 8) & 15];
      uc += rw [i1];  uc -= rw [(i1 + 8) & 15];
      da += rlh[ls1]; da -= rlh[i];
      db += rrh[ls1]; db -= rrh[i];
      dc += rw [ls1]; dc -= rw [i];
      const float o1 = out_px(ua, ub, uc, da, db, dc, rlh[i1], rrh[i1], rw[i1]);

      if (writeOK) {
        d[(size_t)y * WW + cl]       = o0;
        d[(size_t)(y + 1) * WW + cl] = o1;
      }
    }
  }
}

extern "C" void kernel_launch(void* const* d_in, const int* in_sizes, int n_in,
                              void* d_out, int out_size, void* d_ws, size_t ws_size,
                              hipStream_t stream) {
  const float* in = (const float*)d_in[0];
  float* out = (float*)d_out;
  float* ws  = (float*)d_ws;   // 12*1024*1024*4 = 50.3 MB scratch

  dim3 grid(NSTRIP, 16, NIMG);  // 21 strips, 16 ygroups x 2 waves x 32 rows, 12 planes
  dim3 block(128);              // 2-wave workgroups for finer CU packing

  swf_step<<<grid, block, 0, stream>>>(in, out);
  swf_step<<<grid, block, 0, stream>>>(out, ws);
  swf_step<<<grid, block, 0, stream>>>(ws, out);
}